// Round 1
// baseline (208.413 us; speedup 1.0000x reference)
//
#include <hip/hip_runtime.h>
#include <hip/hip_bf16.h>

#define Bb 4
#define Ss 2048
#define Dd 512
#define Hh 8
#define HD 64

typedef __attribute__((ext_vector_type(8))) short bf8_t;   // 8 bf16 (4 VGPRs) MFMA operand
typedef __attribute__((ext_vector_type(4))) float f4_t;    // MFMA accumulator

typedef const unsigned int __attribute__((address_space(1)))* gas_t;
typedef unsigned int __attribute__((address_space(3)))* las_t;

__device__ __forceinline__ short f2bf(float f) {          // RNE f32 -> bf16
  union { float fv; unsigned u; } v; v.fv = f;
  unsigned r = v.u + 0x7fffu + ((v.u >> 16) & 1u);
  return (short)(r >> 16);
}

__device__ __forceinline__ bf8_t pack8(float4 f0, float4 f1) {
  bf8_t v;
  v[0]=f2bf(f0.x); v[1]=f2bf(f0.y); v[2]=f2bf(f0.z); v[3]=f2bf(f0.w);
  v[4]=f2bf(f1.x); v[5]=f2bf(f1.y); v[6]=f2bf(f1.z); v[7]=f2bf(f1.w);
  return v;
}

__device__ __forceinline__ void gload_lds16(const void* g, void* l) {
  __builtin_amdgcn_global_load_lds((gas_t)g, (las_t)l, 16, 0, 0);
}

// ---------------------------------------------------------------------------
// QKV projection: C[m][n] = x[m][:] . W[n][:] + bias[n]   (torch Linear)
// grid (64, 24): x-tile 128 rows, blockIdx.y = proj*8 + head (N-tile = 64)
// Output: Q,K as [b][h][s][hd] bf16 (Q pre-scaled by 0.125); V as [b][h][hd][s]
// ---------------------------------------------------------------------------
__global__ __launch_bounds__(256, 2) void qkv_proj_kernel(
    const float* __restrict__ x,
    const float* __restrict__ Wq, const float* __restrict__ bq,
    const float* __restrict__ Wk, const float* __restrict__ bk,
    const float* __restrict__ Wv, const float* __restrict__ bv,
    short* __restrict__ Qg, short* __restrict__ Kg, short* __restrict__ Vtg)
{
  __shared__ short As[128*64];   // rows of 64 bf16 (128B), 16B-chunk XOR swizzle c^(row&7)
  __shared__ short Bs2[64*64];
  const int p = blockIdx.y >> 3, h = blockIdx.y & 7;
  const float* __restrict__ W    = (p==0) ? Wq : (p==1) ? Wk : Wv;
  const float* __restrict__ bias = (p==0) ? bq : (p==1) ? bk : bv;
  const int m0 = blockIdx.x * 128;
  const int n0 = h * 64;
  const int tid = threadIdx.x;
  const int lane = tid & 63, wid = tid >> 6;
  const int wm = wid & 1, wn = wid >> 1;   // wave -> 64x32 sub-tile of 128x64

  const f4_t zero4 = {0.f, 0.f, 0.f, 0.f};
  f4_t acc[4][2];
  #pragma unroll
  for (int i = 0; i < 4; i++)
    #pragma unroll
    for (int j = 0; j < 2; j++) acc[i][j] = zero4;

  for (int k0 = 0; k0 < Dd; k0 += 64) {
    __syncthreads();
    // stage A (x -> bf16): 128 rows x 64 k, 8 bf16 per chunk, 4 chunks/thread
    #pragma unroll
    for (int i = 0; i < 4; i++) {
      int idx = tid + i*256;
      int row = idx >> 3, c = idx & 7;
      const float* src = x + (size_t)(m0+row)*Dd + k0 + c*8;
      float4 f0 = *(const float4*)src;
      float4 f1 = *(const float4*)(src+4);
      *(bf8_t*)(&As[row*64 + ((c ^ (row&7))*8)]) = pack8(f0, f1);
    }
    // stage B (W -> bf16): 64 rows x 64 k
    #pragma unroll
    for (int i = 0; i < 2; i++) {
      int idx = tid + i*256;
      int row = idx >> 3, c = idx & 7;
      const float* src = W + (size_t)(n0+row)*Dd + k0 + c*8;
      float4 f0 = *(const float4*)src;
      float4 f1 = *(const float4*)(src+4);
      *(bf8_t*)(&Bs2[row*64 + ((c ^ (row&7))*8)]) = pack8(f0, f1);
    }
    __syncthreads();
    #pragma unroll
    for (int ks = 0; ks < 2; ks++) {
      const int cu = ks*4 + (lane>>4);
      bf8_t a[4], bfrag[2];
      #pragma unroll
      for (int mi = 0; mi < 4; mi++) {
        int row = wm*64 + mi*16 + (lane&15);
        a[mi] = *(const bf8_t*)(&As[row*64 + ((cu ^ (row&7))*8)]);
      }
      #pragma unroll
      for (int nf = 0; nf < 2; nf++) {
        int row = wn*32 + nf*16 + (lane&15);
        bfrag[nf] = *(const bf8_t*)(&Bs2[row*64 + ((cu ^ (row&7))*8)]);
      }
      #pragma unroll
      for (int mi = 0; mi < 4; mi++)
        #pragma unroll
        for (int nf = 0; nf < 2; nf++)
          acc[mi][nf] = __builtin_amdgcn_mfma_f32_16x16x32_bf16(a[mi], bfrag[nf], acc[mi][nf], 0, 0, 0);
    }
  }

  // epilogue: bias, (Q: pre-scale by 1/sqrt(HD)), bf16, scatter to ws layouts
  const float qs = (p == 0) ? 0.125f : 1.0f;
  const float badd0 = bias[n0 + wn*32 + (lane&15)];
  const float badd1 = bias[n0 + wn*32 + 16 + (lane&15)];
  #pragma unroll
  for (int mi = 0; mi < 4; mi++) {
    #pragma unroll
    for (int nf = 0; nf < 2; nf++) {
      const int hd = wn*32 + nf*16 + (lane&15);
      const float ba = nf ? badd1 : badd0;
      #pragma unroll
      for (int r = 0; r < 4; r++) {
        int mrow = m0 + wm*64 + mi*16 + (lane>>4)*4 + r;   // C: col=lane&15, row=(lane>>4)*4+r
        int bb = mrow >> 11, ss = mrow & (Ss-1);
        short val = f2bf((acc[mi][nf][r] + ba) * qs);
        if (p == 2)
          Vtg[(((size_t)bb*Hh + h)*HD + hd)*Ss + ss] = val;
        else if (p == 0)
          Qg[(((size_t)bb*Hh + h)*Ss + ss)*HD + hd] = val;
        else
          Kg[(((size_t)bb*Hh + h)*Ss + ss)*HD + hd] = val;
      }
    }
  }
}

// ---------------------------------------------------------------------------
// Flash attention fwd. grid (32, 16): blockIdx.x = b*8+h, blockIdx.y = q-tile.
// 4 waves x 32 q-rows, KV tiles of 32 keys. Online softmax (running m, l).
// K staged [key][hd] (128B rows, c^(row&7) swizzle); V staged [hd][key]
// (64B rows, c^((row>>1)&3) swizzle) — both via global_load_lds with
// pre-swizzled per-lane SOURCE addresses (linear LDS dest).
// ---------------------------------------------------------------------------
__global__ __launch_bounds__(256, 2) void attn_kernel(
    const short* __restrict__ Qg, const short* __restrict__ Kg,
    const short* __restrict__ Vtg, const int* __restrict__ mask,
    float* __restrict__ out)
{
  __shared__ short Ks[32*64];
  __shared__ short Vs[64*32];
  __shared__ short Ps[4][32*32];   // per-wave P tile (swizzled like Vs)
  const int bh = blockIdx.x;
  const int b = bh >> 3, h = bh & 7;
  const int tid = threadIdx.x, lane = tid & 63, w = tid >> 6;
  const short* __restrict__ Qb = Qg + (size_t)bh * Ss * HD;
  const short* __restrict__ Kb = Kg + (size_t)bh * Ss * HD;
  const short* __restrict__ Vb = Vtg + (size_t)bh * HD * Ss;
  const int* __restrict__ maskb = mask + b * Ss;
  const int q0 = blockIdx.y * 128 + w * 32;

  // Q fragments in registers (Q already scaled by 0.125)
  bf8_t qf[2][2];
  #pragma unroll
  for (int mi = 0; mi < 2; mi++)
    #pragma unroll
    for (int ks = 0; ks < 2; ks++)
      qf[mi][ks] = *(const bf8_t*)(Qb + (size_t)(q0 + mi*16 + (lane&15))*HD + ks*32 + (lane>>4)*8);

  const f4_t zero4 = {0.f, 0.f, 0.f, 0.f};
  f4_t o[2][4];
  #pragma unroll
  for (int i = 0; i < 2; i++)
    #pragma unroll
    for (int j = 0; j < 4; j++) o[i][j] = zero4;
  float mrun[2][4], lrun[2][4];
  #pragma unroll
  for (int i = 0; i < 2; i++)
    #pragma unroll
    for (int r = 0; r < 4; r++) { mrun[i][r] = -1e30f; lrun[i][r] = 0.f; }

  // staging: linear LDS dest (wave base + lane*16), swizzle applied on SOURCE
  const int slot = w*64 + lane;
  const int krow = slot >> 3, kc = slot & 7;          // K tile: 32 rows x 8 chunks
  const short* ksrc = Kb + (size_t)krow*HD + ((kc ^ (krow&7))*8);
  const int vrow = slot >> 2, vc = slot & 3;          // V tile: 64 rows x 4 chunks
  const short* vsrc = Vb + (size_t)vrow*Ss + ((vc ^ ((vrow>>1)&3))*8);

  for (int kv0 = 0; kv0 < Ss; kv0 += 32) {
    __syncthreads();                                  // prev-iter LDS reads done
    gload_lds16(ksrc + (size_t)kv0*HD, &Ks[w*512]);
    gload_lds16(vsrc + kv0,            &Vs[w*512]);
    __syncthreads();                                  // vmcnt(0) drained by barrier

    // QK^T: scores (pre-scaled) — C layout: col(key)=lane&15, row(q)=(lane>>4)*4+r
    f4_t sc[2][2];
    sc[0][0] = zero4; sc[0][1] = zero4; sc[1][0] = zero4; sc[1][1] = zero4;
    #pragma unroll
    for (int nf = 0; nf < 2; nf++) {
      const int row = nf*16 + (lane&15);
      #pragma unroll
      for (int ks = 0; ks < 2; ks++) {
        const int cu = ks*4 + (lane>>4);
        bf8_t kf = *(const bf8_t*)(&Ks[row*64 + ((cu ^ (row&7))*8)]);
        sc[0][nf] = __builtin_amdgcn_mfma_f32_16x16x32_bf16(qf[0][ks], kf, sc[0][nf], 0, 0, 0);
        sc[1][nf] = __builtin_amdgcn_mfma_f32_16x16x32_bf16(qf[1][ks], kf, sc[1][nf], 0, 0, 0);
      }
    }
    // mask bias
    float mb[2];
    #pragma unroll
    for (int nf = 0; nf < 2; nf++) {
      int kidx = kv0 + nf*16 + (lane&15);
      mb[nf] = -10000.0f * (1.0f - (float)maskb[kidx]);
    }
    // online softmax
    float pv[2][2][4];
    #pragma unroll
    for (int mi = 0; mi < 2; mi++) {
      float rmax[4], rsum[4];
      #pragma unroll
      for (int r = 0; r < 4; r++) {
        sc[mi][0][r] += mb[0];
        sc[mi][1][r] += mb[1];
        rmax[r] = fmaxf(sc[mi][0][r], sc[mi][1][r]);
      }
      #pragma unroll
      for (int off = 1; off < 16; off <<= 1)
        #pragma unroll
        for (int r = 0; r < 4; r++)
          rmax[r] = fmaxf(rmax[r], __shfl_xor(rmax[r], off, 64));
      #pragma unroll
      for (int r = 0; r < 4; r++) {
        float mnew = fmaxf(mrun[mi][r], rmax[r]);
        float sf = __expf(mrun[mi][r] - mnew);        // exp(-1e30-x) underflows to 0
        mrun[mi][r] = mnew;
        float p0 = __expf(sc[mi][0][r] - mnew);
        float p1 = __expf(sc[mi][1][r] - mnew);
        pv[mi][0][r] = p0; pv[mi][1][r] = p1;
        rsum[r] = p0 + p1;
        lrun[mi][r] *= sf;
        #pragma unroll
        for (int nf = 0; nf < 4; nf++) o[mi][nf][r] *= sf;
      }
      #pragma unroll
      for (int off = 1; off < 16; off <<= 1)
        #pragma unroll
        for (int r = 0; r < 4; r++)
          rsum[r] += __shfl_xor(rsum[r], off, 64);
      #pragma unroll
      for (int r = 0; r < 4; r++) lrun[mi][r] += rsum[r];
    }
    // P (bf16) -> per-wave LDS (swizzled), then read back as MFMA A-frags
    #pragma unroll
    for (int mi = 0; mi < 2; mi++)
      #pragma unroll
      for (int nf = 0; nf < 2; nf++)
        #pragma unroll
        for (int r = 0; r < 4; r++) {
          int prow = mi*16 + (lane>>4)*4 + r;
          int col = nf*16 + (lane&15);
          int cu2 = col >> 3, ci = col & 7;
          Ps[w][prow*32 + ((cu2 ^ ((prow>>1)&3))*8) + ci] = f2bf(pv[mi][nf][r]);
        }
    asm volatile("s_waitcnt lgkmcnt(0)" ::: "memory"); // wave-local P write->read fence
    __builtin_amdgcn_sched_barrier(0);
    bf8_t pf[2];
    #pragma unroll
    for (int mi = 0; mi < 2; mi++) {
      int prow = mi*16 + (lane&15);
      pf[mi] = *(const bf8_t*)(&Ps[w][prow*32 + (((lane>>4) ^ ((prow>>1)&3))*8)]);
    }
    // PV: o += P (32q x 32k) . V (32k x 64hd)
    #pragma unroll
    for (int nf = 0; nf < 4; nf++) {
      int vr = nf*16 + (lane&15);
      bf8_t vf = *(const bf8_t*)(&Vs[vr*32 + (((lane>>4) ^ ((vr>>1)&3))*8)]);
      #pragma unroll
      for (int mi = 0; mi < 2; mi++)
        o[mi][nf] = __builtin_amdgcn_mfma_f32_16x16x32_bf16(pf[mi], vf, o[mi][nf], 0, 0, 0);
    }
  }

  // epilogue: normalize and write h[b][s][h*64+hd] (f32)
  #pragma unroll
  for (int mi = 0; mi < 2; mi++)
    #pragma unroll
    for (int nf = 0; nf < 4; nf++)
      #pragma unroll
      for (int r = 0; r < 4; r++) {
        int srow = q0 + mi*16 + (lane>>4)*4 + r;
        out[((size_t)(b*Ss + srow))*Dd + h*HD + nf*16 + (lane&15)] = o[mi][nf][r] / lrun[mi][r];
      }
}

// ---------------------------------------------------------------------------
extern "C" void kernel_launch(void* const* d_in, const int* in_sizes, int n_in,
                              void* d_out, int out_size, void* d_ws, size_t ws_size,
                              hipStream_t stream) {
  const float* x  = (const float*)d_in[0];
  const int* mask = (const int*)d_in[1];
  const float* Wq = (const float*)d_in[2];
  const float* bq = (const float*)d_in[3];
  const float* Wk = (const float*)d_in[4];
  const float* bk = (const float*)d_in[5];
  const float* Wv = (const float*)d_in[6];
  const float* bv = (const float*)d_in[7];
  float* out = (float*)d_out;

  // workspace: Q | K | Vt, each B*H*S*HD bf16 = 8.39 MB (25.2 MB total)
  short* Qg = (short*)d_ws;
  short* Kg = Qg + (size_t)Bb*Hh*Ss*HD;
  short* Vt = Kg + (size_t)Bb*Hh*Ss*HD;

  qkv_proj_kernel<<<dim3(64, 24), 256, 0, stream>>>(x, Wq, bq, Wk, bk, Wv, bv, Qg, Kg, Vt);
  attn_kernel<<<dim3(32, 16), 256, 0, stream>>>(Qg, Kg, Vt, mask, out);
}

// Round 2
// 168.681 us; speedup vs baseline: 1.2355x; 1.2355x over previous
//
#include <hip/hip_runtime.h>
#include <hip/hip_bf16.h>

#define Bb 4
#define Ss 2048
#define Dd 512
#define Hh 8
#define HD 64

typedef __attribute__((ext_vector_type(8))) short bf8_t;   // 8 bf16 (4 VGPRs) MFMA operand
typedef __attribute__((ext_vector_type(4))) float f4_t;    // MFMA accumulator

typedef const unsigned int __attribute__((address_space(1)))* gas_t;
typedef unsigned int __attribute__((address_space(3)))* las_t;

#define LOG2E 1.44269504088896f

__device__ __forceinline__ short f2bf(float f) {          // RNE f32 -> bf16
  union { float fv; unsigned u; } v; v.fv = f;
  unsigned r = v.u + 0x7fffu + ((v.u >> 16) & 1u);
  return (short)(r >> 16);
}

__device__ __forceinline__ bf8_t pack8(float4 f0, float4 f1) {
  bf8_t v;
  v[0]=f2bf(f0.x); v[1]=f2bf(f0.y); v[2]=f2bf(f0.z); v[3]=f2bf(f0.w);
  v[4]=f2bf(f1.x); v[5]=f2bf(f1.y); v[6]=f2bf(f1.z); v[7]=f2bf(f1.w);
  return v;
}

__device__ __forceinline__ void gload_lds16(const void* g, void* l) {
  __builtin_amdgcn_global_load_lds((gas_t)g, (las_t)l, 16, 0, 0);
}

// ---------------------------------------------------------------------------
// QKV projection: C[m][n] = x[m][:] . W[n][:] + bias[n]   (torch Linear)
// grid (64, 24): x-tile 128 rows, blockIdx.y = proj*8 + head (N-tile = 64)
// Output: Q,K as [b][h][s][hd] bf16 (Q pre-scaled by 0.125*log2e so attention
// can run softmax in exp2 domain); V as [b][h][hd][s]
// ---------------------------------------------------------------------------
__global__ __launch_bounds__(256, 2) void qkv_proj_kernel(
    const float* __restrict__ x,
    const float* __restrict__ Wq, const float* __restrict__ bq,
    const float* __restrict__ Wk, const float* __restrict__ bk,
    const float* __restrict__ Wv, const float* __restrict__ bv,
    short* __restrict__ Qg, short* __restrict__ Kg, short* __restrict__ Vtg)
{
  __shared__ short As[128*64];   // rows of 64 bf16 (128B), 16B-chunk XOR swizzle c^(row&7)
  __shared__ short Bs2[64*64];
  const int p = blockIdx.y >> 3, h = blockIdx.y & 7;
  const float* __restrict__ W    = (p==0) ? Wq : (p==1) ? Wk : Wv;
  const float* __restrict__ bias = (p==0) ? bq : (p==1) ? bk : bv;
  const int m0 = blockIdx.x * 128;
  const int n0 = h * 64;
  const int tid = threadIdx.x;
  const int lane = tid & 63, wid = tid >> 6;
  const int wm = wid & 1, wn = wid >> 1;   // wave -> 64x32 sub-tile of 128x64

  const f4_t zero4 = {0.f, 0.f, 0.f, 0.f};
  f4_t acc[4][2];
  #pragma unroll
  for (int i = 0; i < 4; i++)
    #pragma unroll
    for (int j = 0; j < 2; j++) acc[i][j] = zero4;

  for (int k0 = 0; k0 < Dd; k0 += 64) {
    __syncthreads();
    // stage A (x -> bf16): 128 rows x 64 k, 8 bf16 per chunk, 4 chunks/thread
    #pragma unroll
    for (int i = 0; i < 4; i++) {
      int idx = tid + i*256;
      int row = idx >> 3, c = idx & 7;
      const float* src = x + (size_t)(m0+row)*Dd + k0 + c*8;
      float4 f0 = *(const float4*)src;
      float4 f1 = *(const float4*)(src+4);
      *(bf8_t*)(&As[row*64 + ((c ^ (row&7))*8)]) = pack8(f0, f1);
    }
    // stage B (W -> bf16): 64 rows x 64 k
    #pragma unroll
    for (int i = 0; i < 2; i++) {
      int idx = tid + i*256;
      int row = idx >> 3, c = idx & 7;
      const float* src = W + (size_t)(n0+row)*Dd + k0 + c*8;
      float4 f0 = *(const float4*)src;
      float4 f1 = *(const float4*)(src+4);
      *(bf8_t*)(&Bs2[row*64 + ((c ^ (row&7))*8)]) = pack8(f0, f1);
    }
    __syncthreads();
    #pragma unroll
    for (int ks = 0; ks < 2; ks++) {
      const int cu = ks*4 + (lane>>4);
      bf8_t a[4], bfrag[2];
      #pragma unroll
      for (int mi = 0; mi < 4; mi++) {
        int row = wm*64 + mi*16 + (lane&15);
        a[mi] = *(const bf8_t*)(&As[row*64 + ((cu ^ (row&7))*8)]);
      }
      #pragma unroll
      for (int nf = 0; nf < 2; nf++) {
        int row = wn*32 + nf*16 + (lane&15);
        bfrag[nf] = *(const bf8_t*)(&Bs2[row*64 + ((cu ^ (row&7))*8)]);
      }
      #pragma unroll
      for (int mi = 0; mi < 4; mi++)
        #pragma unroll
        for (int nf = 0; nf < 2; nf++)
          acc[mi][nf] = __builtin_amdgcn_mfma_f32_16x16x32_bf16(a[mi], bfrag[nf], acc[mi][nf], 0, 0, 0);
    }
  }

  // epilogue: bias, (Q: pre-scale by log2e/sqrt(HD)), bf16, scatter to ws layouts
  const float qs = (p == 0) ? 0.125f * LOG2E : 1.0f;
  const float badd0 = bias[n0 + wn*32 + (lane&15)];
  const float badd1 = bias[n0 + wn*32 + 16 + (lane&15)];
  #pragma unroll
  for (int mi = 0; mi < 4; mi++) {
    #pragma unroll
    for (int nf = 0; nf < 2; nf++) {
      const int hd = wn*32 + nf*16 + (lane&15);
      const float ba = nf ? badd1 : badd0;
      #pragma unroll
      for (int r = 0; r < 4; r++) {
        int mrow = m0 + wm*64 + mi*16 + (lane>>4)*4 + r;   // C: col=lane&15, row=(lane>>4)*4+r
        int bb = mrow >> 11, ss = mrow & (Ss-1);
        short val = f2bf((acc[mi][nf][r] + ba) * qs);
        if (p == 2)
          Vtg[(((size_t)bb*Hh + h)*HD + hd)*Ss + ss] = val;
        else if (p == 0)
          Qg[(((size_t)bb*Hh + h)*Ss + ss)*HD + hd] = val;
        else
          Kg[(((size_t)bb*Hh + h)*Ss + ss)*HD + hd] = val;
      }
    }
  }
}

// ---------------------------------------------------------------------------
// Flash attention fwd. grid (32, 32): blockIdx.x = b*8+h, blockIdx.y = q-tile
// of 64 rows. 4 waves x 16 q-rows each, KV tiles of 64 keys. Online softmax
// in exp2 domain (Q pre-scaled by log2e/8), T13 defer-max (THR=11 log2 units).
// K staged [key][hd], V staged [hd][key] — both 128B rows, 16B-chunk XOR
// swizzle c^(row&7), loaded via global_load_lds with pre-swizzled SOURCE
// addresses (linear LDS dest, G21).
// ---------------------------------------------------------------------------
__global__ __launch_bounds__(256, 4) void attn_kernel(
    const short* __restrict__ Qg, const short* __restrict__ Kg,
    const short* __restrict__ Vtg, const int* __restrict__ mask,
    float* __restrict__ out)
{
  __shared__ short Ks[64*64];      // [key][hd]
  __shared__ short Vs[64*64];      // [hd][key]
  __shared__ short Ps[4][16*64];   // per-wave P tile [q][key]
  const int bh = blockIdx.x;
  const int b = bh >> 3, h = bh & 7;
  const int tid = threadIdx.x, lane = tid & 63, w = tid >> 6;
  const short* __restrict__ Qb = Qg + (size_t)bh * Ss * HD;
  const short* __restrict__ Kb = Kg + (size_t)bh * Ss * HD;
  const short* __restrict__ Vb = Vtg + (size_t)bh * HD * Ss;
  const int* __restrict__ maskb = mask + b * Ss;
  const int q0 = blockIdx.y * 64 + w * 16;

  // Q fragments in registers (Q already scaled by 0.125*log2e)
  bf8_t qf[2];
  #pragma unroll
  for (int ks = 0; ks < 2; ks++)
    qf[ks] = *(const bf8_t*)(Qb + (size_t)(q0 + (lane&15))*HD + ks*32 + (lane>>4)*8);

  const f4_t zero4 = {0.f, 0.f, 0.f, 0.f};
  f4_t o[4];
  #pragma unroll
  for (int j = 0; j < 4; j++) o[j] = zero4;
  float mrun[4], lrun[4];
  #pragma unroll
  for (int r = 0; r < 4; r++) { mrun[r] = -1e30f; lrun[r] = 0.f; }

  // staging sources: linear LDS dest (tid*16B), swizzle applied on SOURCE.
  // K tile: 64 rows x 8 chunks = 512 slots; V tile same. 2 gloads each.
  const int sA = tid, sB = tid + 256;
  const short* ksrcA = Kb + (size_t)(sA>>3)*HD + (((sA&7) ^ ((sA>>3)&7))*8);
  const short* ksrcB = Kb + (size_t)(sB>>3)*HD + (((sB&7) ^ ((sB>>3)&7))*8);
  const short* vsrcA = Vb + (size_t)(sA>>3)*Ss + (((sA&7) ^ ((sA>>3)&7))*8);
  const short* vsrcB = Vb + (size_t)(sB>>3)*Ss + (((sB&7) ^ ((sB>>3)&7))*8);

  for (int kv0 = 0; kv0 < Ss; kv0 += 64) {
    __syncthreads();                                  // prev-iter LDS reads done
    gload_lds16(ksrcA + (size_t)kv0*HD, &Ks[sA*8]);
    gload_lds16(ksrcB + (size_t)kv0*HD, &Ks[sB*8]);
    gload_lds16(vsrcA + kv0,            &Vs[sA*8]);
    gload_lds16(vsrcB + kv0,            &Vs[sB*8]);
    __syncthreads();                                  // vmcnt drained by barrier

    // QK^T: C layout col(key)=lane&15, row(q)=(lane>>4)*4+r
    f4_t sc[4];
    #pragma unroll
    for (int nf = 0; nf < 4; nf++) {
      sc[nf] = zero4;
      const int row = nf*16 + (lane&15);
      #pragma unroll
      for (int ks = 0; ks < 2; ks++) {
        const int cu = ks*4 + (lane>>4);
        bf8_t kf = *(const bf8_t*)(&Ks[row*64 + ((cu ^ (row&7))*8)]);
        sc[nf] = __builtin_amdgcn_mfma_f32_16x16x32_bf16(qf[ks], kf, sc[nf], 0, 0, 0);
      }
    }
    // mask bias (log2 domain)
    #pragma unroll
    for (int nf = 0; nf < 4; nf++) {
      int kidx = kv0 + nf*16 + (lane&15);
      float mb = -10000.0f * LOG2E * (1.0f - (float)maskb[kidx]);
      #pragma unroll
      for (int r = 0; r < 4; r++) sc[nf][r] += mb;
    }
    // online softmax (exp2 domain), T13 defer-max
    float rmax[4], rsum[4];
    #pragma unroll
    for (int r = 0; r < 4; r++)
      rmax[r] = fmaxf(fmaxf(sc[0][r], sc[1][r]), fmaxf(sc[2][r], sc[3][r]));
    #pragma unroll
    for (int off = 1; off < 16; off <<= 1)
      #pragma unroll
      for (int r = 0; r < 4; r++)
        rmax[r] = fmaxf(rmax[r], __shfl_xor(rmax[r], off, 64));
    bool grow = false;
    #pragma unroll
    for (int r = 0; r < 4; r++) grow = grow || (rmax[r] > mrun[r] + 11.0f);
    if (__any(grow)) {                                // wave-uniform rescale path
      #pragma unroll
      for (int r = 0; r < 4; r++) {
        float mnew = fmaxf(mrun[r], rmax[r]);
        float sf = exp2f(mrun[r] - mnew);             // exp2(-1e30-x) -> 0
        mrun[r] = mnew;
        lrun[r] *= sf;
        #pragma unroll
        for (int nf = 0; nf < 4; nf++) o[nf][r] *= sf;
      }
    }
    #pragma unroll
    for (int r = 0; r < 4; r++) rsum[r] = 0.f;
    #pragma unroll
    for (int nf = 0; nf < 4; nf++) {
      const int col = nf*16 + (lane&15);
      const int cu2 = col >> 3, ci = col & 7;
      #pragma unroll
      for (int r = 0; r < 4; r++) {
        int prow = (lane>>4)*4 + r;
        float p = exp2f(sc[nf][r] - mrun[r]);         // bounded by 2^11 (defer)
        rsum[r] += p;
        Ps[w][prow*64 + ((cu2 ^ (prow&7))*8) + ci] = f2bf(p);
      }
    }
    #pragma unroll
    for (int off = 1; off < 16; off <<= 1)
      #pragma unroll
      for (int r = 0; r < 4; r++)
        rsum[r] += __shfl_xor(rsum[r], off, 64);
    #pragma unroll
    for (int r = 0; r < 4; r++) lrun[r] += rsum[r];

    asm volatile("s_waitcnt lgkmcnt(0)" ::: "memory"); // wave-local P write->read fence
    __builtin_amdgcn_sched_barrier(0);
    bf8_t pf[2];
    #pragma unroll
    for (int ks2 = 0; ks2 < 2; ks2++) {
      int prow = lane & 15;
      pf[ks2] = *(const bf8_t*)(&Ps[w][prow*64 + (((ks2*4 + (lane>>4)) ^ (prow&7))*8)]);
    }
    // PV: o += P (16q x 64k) . V^T rows (64hd x 64k)
    #pragma unroll
    for (int nf2 = 0; nf2 < 4; nf2++) {
      const int vr = nf2*16 + (lane&15);
      #pragma unroll
      for (int ks2 = 0; ks2 < 2; ks2++) {
        bf8_t vf = *(const bf8_t*)(&Vs[vr*64 + (((ks2*4 + (lane>>4)) ^ (vr&7))*8)]);
        o[nf2] = __builtin_amdgcn_mfma_f32_16x16x32_bf16(pf[ks2], vf, o[nf2], 0, 0, 0);
      }
    }
  }

  // epilogue: normalize and write h[b][s][h*64+hd] (f32)
  #pragma unroll
  for (int nf2 = 0; nf2 < 4; nf2++)
    #pragma unroll
    for (int r = 0; r < 4; r++) {
      int srow = q0 + (lane>>4)*4 + r;
      out[((size_t)(b*Ss + srow))*Dd + h*HD + nf2*16 + (lane&15)] = o[nf2][r] / lrun[r];
    }
}

// ---------------------------------------------------------------------------
extern "C" void kernel_launch(void* const* d_in, const int* in_sizes, int n_in,
                              void* d_out, int out_size, void* d_ws, size_t ws_size,
                              hipStream_t stream) {
  const float* x  = (const float*)d_in[0];
  const int* mask = (const int*)d_in[1];
  const float* Wq = (const float*)d_in[2];
  const float* bq = (const float*)d_in[3];
  const float* Wk = (const float*)d_in[4];
  const float* bk = (const float*)d_in[5];
  const float* Wv = (const float*)d_in[6];
  const float* bv = (const float*)d_in[7];
  float* out = (float*)d_out;

  // workspace: Q | K | Vt, each B*H*S*HD bf16 = 8.39 MB (25.2 MB total)
  short* Qg = (short*)d_ws;
  short* Kg = Qg + (size_t)Bb*Hh*Ss*HD;
  short* Vt = Kg + (size_t)Bb*Hh*Ss*HD;

  qkv_proj_kernel<<<dim3(64, 24), 256, 0, stream>>>(x, Wq, bq, Wk, bk, Wv, bv, Qg, Kg, Vt);
  attn_kernel<<<dim3(32, 32), 256, 0, stream>>>(Qg, Kg, Vt, mask, out);
}

// Round 3
// 136.314 us; speedup vs baseline: 1.5289x; 1.2374x over previous
//
#include <hip/hip_runtime.h>
#include <hip/hip_bf16.h>

#define Bb 4
#define Ss 2048
#define Dd 512
#define Hh 8
#define HD 64
#define NX (Bb*Ss*Dd)   // 4194304 x elems
#define NW (3*Dd*Dd)    // 786432 weight elems

typedef __attribute__((ext_vector_type(8))) short bf8_t;   // 8 bf16 (4 VGPRs) MFMA operand
typedef __attribute__((ext_vector_type(4))) float f4_t;    // MFMA accumulator

typedef const unsigned int __attribute__((address_space(1)))* gas_t;
typedef unsigned int __attribute__((address_space(3)))* las_t;

#define LOG2E 1.44269504088896f
#define MBIAS_C (-10000.0f * LOG2E)

__device__ __forceinline__ short cvt1(float f) {           // f32 -> bf16 (native RNE)
  __hip_bfloat16 h = __float2bfloat16(f);
  union { __hip_bfloat16 hh; short ss; } u; u.hh = h; return u.ss;
}

__device__ __forceinline__ bf8_t pack8(float4 f0, float4 f1) {
  bf8_t v;
  v[0]=cvt1(f0.x); v[1]=cvt1(f0.y); v[2]=cvt1(f0.z); v[3]=cvt1(f0.w);
  v[4]=cvt1(f1.x); v[5]=cvt1(f1.y); v[6]=cvt1(f1.z); v[7]=cvt1(f1.w);
  return v;
}

__device__ __forceinline__ void gload_lds16(const void* g, void* l) {
  __builtin_amdgcn_global_load_lds((gas_t)g, (las_t)l, 16, 0, 0);
}

// ---------------------------------------------------------------------------
// f32 -> bf16 conversion for x and the three weight matrices.
// grid 2432 x 256, each thread converts 8 contiguous elements.
// ---------------------------------------------------------------------------
__global__ __launch_bounds__(256) void convert_kernel(
    const float* __restrict__ x, const float* __restrict__ Wq,
    const float* __restrict__ Wk, const float* __restrict__ Wv,
    short* __restrict__ xb, short* __restrict__ Wb)
{
  size_t i = ((size_t)blockIdx.x * 256 + threadIdx.x) * 8;
  const float* src; short* dst;
  if (i < (size_t)NX) { src = x + i; dst = xb + i; }
  else {
    size_t j = i - NX;
    int ws = (int)(j >> 18);                 // 262144 elems per W
    const float* W = (ws == 0) ? Wq : (ws == 1) ? Wk : Wv;
    src = W + (j & 0x3FFFF); dst = Wb + j;
  }
  float4 f0 = *(const float4*)src;
  float4 f1 = *(const float4*)(src + 4);
  *(bf8_t*)dst = pack8(f0, f1);
}

// ---------------------------------------------------------------------------
// QKV projection from bf16 x/W: C[m][n] = x[m][:] . W[n][:] + bias[n]
// grid (64, 24): 128-row x-tile, blockIdx.y = proj*8 + head (N = 64).
// Staging via global_load_lds (16B), 2-phase double-buffered pipeline.
// Output: Q,K as [b][h][s][hd] bf16 (Q pre-scaled by 0.125*log2e); V as
// [b][h][hd][s].
// ---------------------------------------------------------------------------
__global__ __launch_bounds__(256, 2) void qkv_proj_kernel(
    const short* __restrict__ xb, const short* __restrict__ Wb,
    const float* __restrict__ bq, const float* __restrict__ bk,
    const float* __restrict__ bv,
    short* __restrict__ Qg, short* __restrict__ Kg, short* __restrict__ Vtg)
{
  __shared__ short As[2][128*64];   // 16B-chunk XOR swizzle c^(row&7)
  __shared__ short Bs2[2][64*64];
  const int p = blockIdx.y >> 3, h = blockIdx.y & 7;
  const short* __restrict__ W = Wb + (size_t)p * Dd * Dd;
  const float* __restrict__ bias = (p==0) ? bq : (p==1) ? bk : bv;
  const int m0 = blockIdx.x * 128;
  const int n0 = h * 64;
  const int tid = threadIdx.x;
  const int lane = tid & 63, wid = tid >> 6;
  const int wm = wid & 1, wn = wid >> 1;    // wave -> 64x32 sub-tile

  // pre-swizzled staging sources (chunk c of row -> global chunk c^(row&7))
  const short* aSrc[4];
  #pragma unroll
  for (int i = 0; i < 4; i++) {
    int slot = tid + i*256, row = slot >> 3, c = slot & 7;
    aSrc[i] = xb + (size_t)(m0 + row)*Dd + ((c ^ (row&7))*8);
  }
  const short* bSrc[2];
  #pragma unroll
  for (int i = 0; i < 2; i++) {
    int slot = tid + i*256, row = slot >> 3, c = slot & 7;
    bSrc[i] = W + (size_t)(n0 + row)*Dd + ((c ^ (row&7))*8);
  }

  const f4_t zero4 = {0.f, 0.f, 0.f, 0.f};
  f4_t acc[4][2];
  #pragma unroll
  for (int i = 0; i < 4; i++)
    #pragma unroll
    for (int j = 0; j < 2; j++) acc[i][j] = zero4;

  auto STAGE = [&](int bufi, int k0) {
    #pragma unroll
    for (int i = 0; i < 4; i++) gload_lds16(aSrc[i] + k0, &As[bufi][(tid + i*256)*8]);
    #pragma unroll
    for (int i = 0; i < 2; i++) gload_lds16(bSrc[i] + k0, &Bs2[bufi][(tid + i*256)*8]);
  };

  STAGE(0, 0);
  __syncthreads();
  for (int kt = 0; kt < 8; kt++) {
    const int cur = kt & 1;
    if (kt < 7) STAGE(cur ^ 1, (kt + 1)*64);
    #pragma unroll
    for (int ks = 0; ks < 2; ks++) {
      const int cu = ks*4 + (lane>>4);
      bf8_t a[4], bfrag[2];
      #pragma unroll
      for (int mi = 0; mi < 4; mi++) {
        int row = wm*64 + mi*16 + (lane&15);
        a[mi] = *(const bf8_t*)(&As[cur][row*64 + ((cu ^ (row&7))*8)]);
      }
      #pragma unroll
      for (int nf = 0; nf < 2; nf++) {
        int row = wn*32 + nf*16 + (lane&15);
        bfrag[nf] = *(const bf8_t*)(&Bs2[cur][row*64 + ((cu ^ (row&7))*8)]);
      }
      #pragma unroll
      for (int mi = 0; mi < 4; mi++)
        #pragma unroll
        for (int nf = 0; nf < 2; nf++)
          acc[mi][nf] = __builtin_amdgcn_mfma_f32_16x16x32_bf16(a[mi], bfrag[nf], acc[mi][nf], 0, 0, 0);
    }
    __syncthreads();
  }

  // epilogue: bias, (Q: pre-scale by log2e/8), bf16, scatter
  const float qs = (p == 0) ? 0.125f * LOG2E : 1.0f;
  const float badd0 = bias[n0 + wn*32 + (lane&15)];
  const float badd1 = bias[n0 + wn*32 + 16 + (lane&15)];
  #pragma unroll
  for (int mi = 0; mi < 4; mi++) {
    #pragma unroll
    for (int nf = 0; nf < 2; nf++) {
      const int hd = wn*32 + nf*16 + (lane&15);
      const float ba = nf ? badd1 : badd0;
      #pragma unroll
      for (int r = 0; r < 4; r++) {
        int mrow = m0 + wm*64 + mi*16 + (lane>>4)*4 + r;
        int bb = mrow >> 11, ss = mrow & (Ss-1);
        short val = cvt1((acc[mi][nf][r] + ba) * qs);
        if (p == 2)
          Vtg[(((size_t)bb*Hh + h)*HD + hd)*Ss + ss] = val;
        else if (p == 0)
          Qg[(((size_t)bb*Hh + h)*Ss + ss)*HD + hd] = val;
        else
          Kg[(((size_t)bb*Hh + h)*Ss + ss)*HD + hd] = val;
      }
    }
  }
}

// ---------------------------------------------------------------------------
// Flash attention fwd. grid (32, 32): blockIdx.x = b*8+h, blockIdx.y = 64-row
// q-tile. 4 waves x 16 q-rows, KV tiles of 64 keys, 2-phase double-buffered
// staging (issue next-tile gload_lds before compute, one barrier/tile).
// exp2-domain online softmax, T13 defer-max (THR=11), row-sum via
// MFMA-with-ones accumulated across tiles, mask bias in LDS with
// wave-uniform skip.
// ---------------------------------------------------------------------------
__global__ __launch_bounds__(256, 2) void attn_kernel(
    const short* __restrict__ Qg, const short* __restrict__ Kg,
    const short* __restrict__ Vtg, const int* __restrict__ mask,
    float* __restrict__ out)
{
  __shared__ short Ks[2][64*64];   // [key][hd], swizzled
  __shared__ short Vs[2][64*64];   // [hd][key], swizzled
  __shared__ short Ps[4][16*64];   // per-wave P tile [q][key], swizzled
  __shared__ float mb_lds[Ss];     // per-key mask bias (log2 domain)
  const int bh = blockIdx.x;
  const int b = bh >> 3, h = bh & 7;
  const int tid = threadIdx.x, lane = tid & 63, w = tid >> 6;
  const short* __restrict__ Qb = Qg + (size_t)bh * Ss * HD;
  const short* __restrict__ Kb = Kg + (size_t)bh * Ss * HD;
  const short* __restrict__ Vb = Vtg + (size_t)bh * HD * Ss;
  const int* __restrict__ maskb = mask + b * Ss;
  const int q0 = blockIdx.y * 64 + w * 16;

  // Q fragments (Q already scaled by 0.125*log2e)
  bf8_t qf[2];
  #pragma unroll
  for (int ks = 0; ks < 2; ks++)
    qf[ks] = *(const bf8_t*)(Qb + (size_t)(q0 + (lane&15))*HD + ks*32 + (lane>>4)*8);

  const f4_t zero4 = {0.f, 0.f, 0.f, 0.f};
  f4_t o[4];
  #pragma unroll
  for (int j = 0; j < 4; j++) o[j] = zero4;
  f4_t lacc = zero4;                        // row-sum accumulator (MFMA-ones)
  float mrun[4];
  #pragma unroll
  for (int r = 0; r < 4; r++) mrun[r] = -1e30f;

  const bf8_t ones = {(short)0x3F80,(short)0x3F80,(short)0x3F80,(short)0x3F80,
                      (short)0x3F80,(short)0x3F80,(short)0x3F80,(short)0x3F80};

  // mask bias -> LDS (once per block)
  {
    int idx = tid * 8;
    int4 m0 = *(const int4*)(maskb + idx);
    int4 m1 = *(const int4*)(maskb + idx + 4);
    float4 b0 = { MBIAS_C*(1.f-(float)m0.x), MBIAS_C*(1.f-(float)m0.y),
                  MBIAS_C*(1.f-(float)m0.z), MBIAS_C*(1.f-(float)m0.w) };
    float4 b1 = { MBIAS_C*(1.f-(float)m1.x), MBIAS_C*(1.f-(float)m1.y),
                  MBIAS_C*(1.f-(float)m1.z), MBIAS_C*(1.f-(float)m1.w) };
    *(float4*)&mb_lds[idx] = b0;
    *(float4*)&mb_lds[idx+4] = b1;
  }

  // staging sources: linear LDS dest, swizzle pre-applied on SOURCE (G21)
  const int sA = tid, sB = tid + 256;
  const short* ksrcA = Kb + (size_t)(sA>>3)*HD + (((sA&7) ^ ((sA>>3)&7))*8);
  const short* ksrcB = Kb + (size_t)(sB>>3)*HD + (((sB&7) ^ ((sB>>3)&7))*8);
  const short* vsrcA = Vb + (size_t)(sA>>3)*Ss + (((sA&7) ^ ((sA>>3)&7))*8);
  const short* vsrcB = Vb + (size_t)(sB>>3)*Ss + (((sB&7) ^ ((sB>>3)&7))*8);

  auto STAGE = [&](int bufi, int kv) {
    gload_lds16(ksrcA + (size_t)kv*HD, &Ks[bufi][sA*8]);
    gload_lds16(ksrcB + (size_t)kv*HD, &Ks[bufi][sB*8]);
    gload_lds16(vsrcA + kv,            &Vs[bufi][sA*8]);
    gload_lds16(vsrcB + kv,            &Vs[bufi][sB*8]);
  };

  STAGE(0, 0);
  __syncthreads();
  for (int t = 0; t < Ss/64; t++) {
    const int cur = t & 1;
    if (t + 1 < Ss/64) STAGE(cur ^ 1, (t + 1)*64);
    const float mbl = mb_lds[t*64 + lane];            // bias for key t*64+lane

    // QK^T: C col(key)=lane&15, row(q)=(lane>>4)*4+r
    f4_t sc[4];
    #pragma unroll
    for (int nf = 0; nf < 4; nf++) {
      sc[nf] = zero4;
      const int row = nf*16 + (lane&15);
      #pragma unroll
      for (int ks = 0; ks < 2; ks++) {
        const int cu = ks*4 + (lane>>4);
        bf8_t kf = *(const bf8_t*)(&Ks[cur][row*64 + ((cu ^ (row&7))*8)]);
        sc[nf] = __builtin_amdgcn_mfma_f32_16x16x32_bf16(qf[ks], kf, sc[nf], 0, 0, 0);
      }
    }
    if (__any(mbl != 0.0f)) {                         // masked keys present
      #pragma unroll
      for (int nf = 0; nf < 4; nf++) {
        float mbv = __shfl(mbl, nf*16 + (lane&15), 64);
        #pragma unroll
        for (int r = 0; r < 4; r++) sc[nf][r] += mbv;
      }
    }
    // online softmax (exp2 domain), defer-max
    float rmax[4];
    #pragma unroll
    for (int r = 0; r < 4; r++)
      rmax[r] = fmaxf(fmaxf(sc[0][r], sc[1][r]), fmaxf(sc[2][r], sc[3][r]));
    #pragma unroll
    for (int off = 1; off < 16; off <<= 1)
      #pragma unroll
      for (int r = 0; r < 4; r++)
        rmax[r] = fmaxf(rmax[r], __shfl_xor(rmax[r], off, 64));
    bool grow = false;
    #pragma unroll
    for (int r = 0; r < 4; r++) grow = grow || (rmax[r] > mrun[r] + 11.0f);
    if (__any(grow)) {
      #pragma unroll
      for (int r = 0; r < 4; r++) {
        float mnew = fmaxf(mrun[r], rmax[r]);
        float sf = __builtin_amdgcn_exp2f(mrun[r] - mnew);
        mrun[r] = mnew;
        lacc[r] *= sf;
        #pragma unroll
        for (int nf = 0; nf < 4; nf++) o[nf][r] *= sf;
      }
    }
    // P = exp2(sc - mrun), bf16 -> per-wave LDS (swizzled)
    #pragma unroll
    for (int nf = 0; nf < 4; nf++) {
      const int col = nf*16 + (lane&15);
      const int cu2 = col >> 3, ci = col & 7;
      #pragma unroll
      for (int r = 0; r < 4; r++) {
        int prow = (lane>>4)*4 + r;
        float p = __builtin_amdgcn_exp2f(sc[nf][r] - mrun[r]);   // <= 2^11
        Ps[w][prow*64 + ((cu2 ^ (prow&7))*8) + ci] = cvt1(p);
      }
    }
    asm volatile("s_waitcnt lgkmcnt(0)" ::: "memory"); // wave-local fence
    __builtin_amdgcn_sched_barrier(0);
    bf8_t pf[2];
    #pragma unroll
    for (int ks2 = 0; ks2 < 2; ks2++) {
      int prow = lane & 15;
      pf[ks2] = *(const bf8_t*)(&Ps[w][prow*64 + (((ks2*4 + (lane>>4)) ^ (prow&7))*8)]);
    }
    // row-sum via MFMA-with-ones (accumulates across tiles)
    lacc = __builtin_amdgcn_mfma_f32_16x16x32_bf16(pf[0], ones, lacc, 0, 0, 0);
    lacc = __builtin_amdgcn_mfma_f32_16x16x32_bf16(pf[1], ones, lacc, 0, 0, 0);
    // PV: o += P (16q x 64k) . V^T (64hd x 64k)
    #pragma unroll
    for (int nf2 = 0; nf2 < 4; nf2++) {
      const int vr = nf2*16 + (lane&15);
      #pragma unroll
      for (int ks2 = 0; ks2 < 2; ks2++) {
        bf8_t vf = *(const bf8_t*)(&Vs[cur][vr*64 + (((ks2*4 + (lane>>4)) ^ (vr&7))*8)]);
        o[nf2] = __builtin_amdgcn_mfma_f32_16x16x32_bf16(pf[ks2], vf, o[nf2], 0, 0, 0);
      }
    }
    __syncthreads();
  }

  // epilogue: normalize and write h[b][s][h*64+hd] (f32)
  #pragma unroll
  for (int nf2 = 0; nf2 < 4; nf2++)
    #pragma unroll
    for (int r = 0; r < 4; r++) {
      int srow = q0 + (lane>>4)*4 + r;
      out[((size_t)(b*Ss + srow))*Dd + h*HD + nf2*16 + (lane&15)] = o[nf2][r] / lacc[r];
    }
}

// ---------------------------------------------------------------------------
extern "C" void kernel_launch(void* const* d_in, const int* in_sizes, int n_in,
                              void* d_out, int out_size, void* d_ws, size_t ws_size,
                              hipStream_t stream) {
  const float* x  = (const float*)d_in[0];
  const int* mask = (const int*)d_in[1];
  const float* Wq = (const float*)d_in[2];
  const float* bq = (const float*)d_in[3];
  const float* Wk = (const float*)d_in[4];
  const float* bk = (const float*)d_in[5];
  const float* Wv = (const float*)d_in[6];
  const float* bv = (const float*)d_in[7];
  float* out = (float*)d_out;

  // ws: Q | K | Vt (each 4.19M shorts) | xb (4.19M) | Wb (786K)  ~= 35 MB
  short* Qg = (short*)d_ws;
  short* Kg = Qg + (size_t)Bb*Hh*Ss*HD;
  short* Vt = Kg + (size_t)Bb*Hh*Ss*HD;
  short* xb = Vt + (size_t)Bb*Hh*Ss*HD;
  short* Wb = xb + (size_t)NX;

  convert_kernel<<<dim3((NX + NW)/2048), 256, 0, stream>>>(x, Wq, Wk, Wv, xb, Wb);
  qkv_proj_kernel<<<dim3(64, 24), 256, 0, stream>>>(xb, Wb, bq, bk, bv, Qg, Kg, Vt);
  attn_kernel<<<dim3(32, 32), 256, 0, stream>>>(Qg, Kg, Vt, mask, out);
}

// Round 5
// 104.424 us; speedup vs baseline: 1.9958x; 1.3054x over previous
//
#include <hip/hip_runtime.h>
#include <hip/hip_bf16.h>

#define Bb 4
#define Ss 2048
#define Dd 512
#define Hh 8
#define HD 64
#define NX (Bb*Ss*Dd)   // 4194304 x elems
#define NW (3*Dd*Dd)    // 786432 weight elems

typedef __attribute__((ext_vector_type(8))) short bf8_t;   // 8 bf16 (4 VGPRs) MFMA operand
typedef __attribute__((ext_vector_type(4))) float f4_t;    // MFMA accumulator
typedef unsigned int u32;
typedef __attribute__((ext_vector_type(2))) unsigned int u32x2;
typedef __attribute__((ext_vector_type(4))) unsigned int u32x4;

typedef const unsigned int __attribute__((address_space(1)))* gas_t;
typedef unsigned int __attribute__((address_space(3)))* las_t;

#define LOG2E 1.44269504088896f
#define MBIAS_C (-10000.0f * LOG2E)

__device__ __forceinline__ short cvt1(float f) {           // f32 -> bf16 (native RNE)
  __hip_bfloat16 h = __float2bfloat16(f);
  union { __hip_bfloat16 hh; short ss; } u; u.hh = h; return u.ss;
}

__device__ __forceinline__ bf8_t pack8(float4 f0, float4 f1) {
  bf8_t v;
  v[0]=cvt1(f0.x); v[1]=cvt1(f0.y); v[2]=cvt1(f0.z); v[3]=cvt1(f0.w);
  v[4]=cvt1(f1.x); v[5]=cvt1(f1.y); v[6]=cvt1(f1.z); v[7]=cvt1(f1.w);
  return v;
}

__device__ __forceinline__ void gload_lds16(const void* g, void* l) {
  __builtin_amdgcn_global_load_lds((gas_t)g, (las_t)l, 16, 0, 0);
}

// ds_read_b64_tr_b16: each lane fetches 64b at its own addr; HW exchanges
// 16-bit elems within each 16-lane group. For a 4x16 row-major bf16 tile at
// tile_base, pass addr_l = tile_base + (lane&15)*8B; lane l receives
// tile[row j][col lane&15] in elems j=0..3 (m156 formula reconstruction).
__device__ __forceinline__ u32x2 tr16(const short* p) {
  u32x2 r;
  unsigned a = (unsigned)(uintptr_t)(las_t)p;
  asm volatile("ds_read_b64_tr_b16 %0, %1" : "=v"(r) : "v"(a));
  return r;
}

// ---------------------------------------------------------------------------
// f32 -> bf16 conversion for x and the three weight matrices.
// ---------------------------------------------------------------------------
__global__ __launch_bounds__(256) void convert_kernel(
    const float* __restrict__ x, const float* __restrict__ Wq,
    const float* __restrict__ Wk, const float* __restrict__ Wv,
    short* __restrict__ xb, short* __restrict__ Wb)
{
  size_t i = ((size_t)blockIdx.x * 256 + threadIdx.x) * 8;
  const float* src; short* dst;
  if (i < (size_t)NX) { src = x + i; dst = xb + i; }
  else {
    size_t j = i - NX;
    int ws = (int)(j >> 18);                 // 262144 elems per W
    const float* W = (ws == 0) ? Wq : (ws == 1) ? Wk : Wv;
    src = W + (j & 0x3FFFF); dst = Wb + j;
  }
  float4 f0 = *(const float4*)src;
  float4 f1 = *(const float4*)(src + 4);
  *(bf8_t*)dst = pack8(f0, f1);
}

// ---------------------------------------------------------------------------
// QKV projection from bf16 x/W. grid (64, 24). 2-phase dbuf via gload_lds.
// Q,K out [b][h][s][hd] (Q pre-scaled by log2e/8); V out [b][h][hd][s].
// ---------------------------------------------------------------------------
__global__ __launch_bounds__(256, 2) void qkv_proj_kernel(
    const short* __restrict__ xb, const short* __restrict__ Wb,
    const float* __restrict__ bq, const float* __restrict__ bk,
    const float* __restrict__ bv,
    short* __restrict__ Qg, short* __restrict__ Kg, short* __restrict__ Vtg)
{
  __shared__ short As[2][128*64];   // 16B-chunk XOR swizzle c^(row&7)
  __shared__ short Bs2[2][64*64];
  const int p = blockIdx.y >> 3, h = blockIdx.y & 7;
  const short* __restrict__ W = Wb + (size_t)p * Dd * Dd;
  const float* __restrict__ bias = (p==0) ? bq : (p==1) ? bk : bv;
  const int m0 = blockIdx.x * 128;
  const int n0 = h * 64;
  const int tid = threadIdx.x;
  const int lane = tid & 63, wid = tid >> 6;
  const int wm = wid & 1, wn = wid >> 1;    // wave -> 64x32 sub-tile

  const short* aSrc[4];
  #pragma unroll
  for (int i = 0; i < 4; i++) {
    int slot = tid + i*256, row = slot >> 3, c = slot & 7;
    aSrc[i] = xb + (size_t)(m0 + row)*Dd + ((c ^ (row&7))*8);
  }
  const short* bSrc[2];
  #pragma unroll
  for (int i = 0; i < 2; i++) {
    int slot = tid + i*256, row = slot >> 3, c = slot & 7;
    bSrc[i] = W + (size_t)(n0 + row)*Dd + ((c ^ (row&7))*8);
  }

  const f4_t zero4 = {0.f, 0.f, 0.f, 0.f};
  f4_t acc[4][2];
  #pragma unroll
  for (int i = 0; i < 4; i++)
    #pragma unroll
    for (int j = 0; j < 2; j++) acc[i][j] = zero4;

  auto STAGE = [&](int bufi, int k0) {
    #pragma unroll
    for (int i = 0; i < 4; i++) gload_lds16(aSrc[i] + k0, &As[bufi][(tid + i*256)*8]);
    #pragma unroll
    for (int i = 0; i < 2; i++) gload_lds16(bSrc[i] + k0, &Bs2[bufi][(tid + i*256)*8]);
  };

  STAGE(0, 0);
  __syncthreads();
  for (int kt = 0; kt < 8; kt++) {
    const int cur = kt & 1;
    if (kt < 7) STAGE(cur ^ 1, (kt + 1)*64);
    #pragma unroll
    for (int ks = 0; ks < 2; ks++) {
      const int cu = ks*4 + (lane>>4);
      bf8_t a[4], bfrag[2];
      #pragma unroll
      for (int mi = 0; mi < 4; mi++) {
        int row = wm*64 + mi*16 + (lane&15);
        a[mi] = *(const bf8_t*)(&As[cur][row*64 + ((cu ^ (row&7))*8)]);
      }
      #pragma unroll
      for (int nf = 0; nf < 2; nf++) {
        int row = wn*32 + nf*16 + (lane&15);
        bfrag[nf] = *(const bf8_t*)(&Bs2[cur][row*64 + ((cu ^ (row&7))*8)]);
      }
      #pragma unroll
      for (int mi = 0; mi < 4; mi++)
        #pragma unroll
        for (int nf = 0; nf < 2; nf++)
          acc[mi][nf] = __builtin_amdgcn_mfma_f32_16x16x32_bf16(a[mi], bfrag[nf], acc[mi][nf], 0, 0, 0);
    }
    __syncthreads();
  }

  const float qs = (p == 0) ? 0.125f * LOG2E : 1.0f;
  const float badd0 = bias[n0 + wn*32 + (lane&15)];
  const float badd1 = bias[n0 + wn*32 + 16 + (lane&15)];
  #pragma unroll
  for (int mi = 0; mi < 4; mi++) {
    #pragma unroll
    for (int nf = 0; nf < 2; nf++) {
      const int hd = wn*32 + nf*16 + (lane&15);
      const float ba = nf ? badd1 : badd0;
      #pragma unroll
      for (int r = 0; r < 4; r++) {
        int mrow = m0 + wm*64 + mi*16 + (lane>>4)*4 + r;
        int bb = mrow >> 11, ss = mrow & (Ss-1);
        short val = cvt1((acc[mi][nf][r] + ba) * qs);
        if (p == 2)
          Vtg[(((size_t)bb*Hh + h)*HD + hd)*Ss + ss] = val;
        else if (p == 0)
          Qg[(((size_t)bb*Hh + h)*Ss + ss)*HD + hd] = val;
        else
          Kg[(((size_t)bb*Hh + h)*Ss + ss)*HD + hd] = val;
      }
    }
  }
}

// ---------------------------------------------------------------------------
// Flash attention fwd. grid (32, 32): blockIdx.x = b*8+h, blockIdx.y = 64-row
// q-tile. 4 waves x 16 q-rows, KV tiles of 64 keys, 2-phase dbuf staging.
// exp2-domain online softmax; defer-max with shuffle-free local check;
// row-sum via MFMA-with-ones; P transposed in LDS ([key][q], ds_write_b64)
// and read back as A-frags via ds_read_b64_tr_b16 with per-lane addr
// tile_base + lq*8B (fixed from round 4). LDS = 40 KB -> 4 blocks/CU.
// ---------------------------------------------------------------------------
__global__ __launch_bounds__(256, 4) void attn_kernel(
    const short* __restrict__ Qg, const short* __restrict__ Kg,
    const short* __restrict__ Vtg, const int* __restrict__ mask,
    float* __restrict__ out)
{
  __shared__ short Ks[2][64*64];   // [key][hd], swizzled
  __shared__ short Vs[2][64*64];   // [hd][key], swizzled
  __shared__ short Ps[4][64*16];   // per-wave P^T tile [key][q]
  const int bh = blockIdx.x;
  const int b = bh >> 3, h = bh & 7;
  const int tid = threadIdx.x, lane = tid & 63, w = tid >> 6;
  const int hi = lane >> 4, lq = lane & 15;
  const short* __restrict__ Qb = Qg + (size_t)bh * Ss * HD;
  const short* __restrict__ Kb = Kg + (size_t)bh * Ss * HD;
  const short* __restrict__ Vb = Vtg + (size_t)bh * HD * Ss;
  const int* __restrict__ maskb = mask + b * Ss;
  const int q0 = blockIdx.y * 64 + w * 16;

  // Q fragments (Q already scaled by 0.125*log2e)
  bf8_t qf[2];
  #pragma unroll
  for (int ks = 0; ks < 2; ks++)
    qf[ks] = *(const bf8_t*)(Qb + (size_t)(q0 + lq)*HD + ks*32 + hi*8);

  const f4_t zero4 = {0.f, 0.f, 0.f, 0.f};
  f4_t o[4];
  #pragma unroll
  for (int j = 0; j < 4; j++) o[j] = zero4;
  f4_t lacc = zero4;                        // row-sum accumulator (MFMA-ones)
  float mrun[4];
  #pragma unroll
  for (int r = 0; r < 4; r++) mrun[r] = -1e30f;

  const bf8_t ones = {(short)0x3F80,(short)0x3F80,(short)0x3F80,(short)0x3F80,
                      (short)0x3F80,(short)0x3F80,(short)0x3F80,(short)0x3F80};

  // staging sources: linear LDS dest, swizzle pre-applied on SOURCE (G21)
  const int sA = tid, sB = tid + 256;
  const short* ksrcA = Kb + (size_t)(sA>>3)*HD + (((sA&7) ^ ((sA>>3)&7))*8);
  const short* ksrcB = Kb + (size_t)(sB>>3)*HD + (((sB&7) ^ ((sB>>3)&7))*8);
  const short* vsrcA = Vb + (size_t)(sA>>3)*Ss + (((sA&7) ^ ((sA>>3)&7))*8);
  const short* vsrcB = Vb + (size_t)(sB>>3)*Ss + (((sB&7) ^ ((sB>>3)&7))*8);

  auto STAGE = [&](int bufi, int kv) {
    gload_lds16(ksrcA + (size_t)kv*HD, &Ks[bufi][sA*8]);
    gload_lds16(ksrcB + (size_t)kv*HD, &Ks[bufi][sB*8]);
    gload_lds16(vsrcA + kv,            &Vs[bufi][sA*8]);
    gload_lds16(vsrcB + kv,            &Vs[bufi][sB*8]);
  };

  STAGE(0, 0);
  __syncthreads();
  for (int t = 0; t < Ss/64; t++) {
    const int cur = t & 1;
    if (t + 1 < Ss/64) STAGE(cur ^ 1, (t + 1)*64);
    const int mv = maskb[t*64 + lane];                // issued early, used late
    // QK^T: C col(key)=lq, row(q)=hi*4+r
    f4_t sc[4];
    #pragma unroll
    for (int nf = 0; nf < 4; nf++) {
      sc[nf] = zero4;
      const int row = nf*16 + lq;
      #pragma unroll
      for (int ks = 0; ks < 2; ks++) {
        const int cu = ks*4 + hi;
        bf8_t kf = *(const bf8_t*)(&Ks[cur][row*64 + ((cu ^ (row&7))*8)]);
        sc[nf] = __builtin_amdgcn_mfma_f32_16x16x32_bf16(qf[ks], kf, sc[nf], 0, 0, 0);
      }
    }
    const float mbl = MBIAS_C * (1.0f - (float)mv);   // bias of key t*64+lane
    if (__any(mbl != 0.0f)) {                         // masked keys present (rare)
      #pragma unroll
      for (int nf = 0; nf < 4; nf++) {
        float mbv = __shfl(mbl, nf*16 + lq, 64);
        #pragma unroll
        for (int r = 0; r < 4; r++) sc[nf][r] += mbv;
      }
    }
    // defer-max: shuffle-free local growth check (common path: no reduce)
    bool grow = false;
    #pragma unroll
    for (int r = 0; r < 4; r++) {
      float lmax = fmaxf(fmaxf(sc[0][r], sc[1][r]), fmaxf(sc[2][r], sc[3][r]));
      grow = grow || (lmax > mrun[r] + 11.0f);
    }
    if (__any(grow)) {                                // rare: full reduce + rescale
      float rmax[4];
      #pragma unroll
      for (int r = 0; r < 4; r++)
        rmax[r] = fmaxf(fmaxf(sc[0][r], sc[1][r]), fmaxf(sc[2][r], sc[3][r]));
      #pragma unroll
      for (int off = 1; off < 16; off <<= 1)
        #pragma unroll
        for (int r = 0; r < 4; r++)
          rmax[r] = fmaxf(rmax[r], __shfl_xor(rmax[r], off, 64));
      #pragma unroll
      for (int r = 0; r < 4; r++) {
        float mnew = fmaxf(mrun[r], rmax[r]);
        float sf = __builtin_amdgcn_exp2f(mrun[r] - mnew);
        mrun[r] = mnew;
        lacc[r] *= sf;
        #pragma unroll
        for (int nf = 0; nf < 4; nf++) o[nf][r] *= sf;
      }
    }
    // P = exp2(sc - mrun) -> bf16 -> P^T LDS [key][q]: one b64 write per nf
    #pragma unroll
    for (int nf = 0; nf < 4; nf++) {
      const int key = nf*16 + lq;
      float p0 = __builtin_amdgcn_exp2f(sc[nf][0] - mrun[0]);
      float p1 = __builtin_amdgcn_exp2f(sc[nf][1] - mrun[1]);
      float p2 = __builtin_amdgcn_exp2f(sc[nf][2] - mrun[2]);
      float p3 = __builtin_amdgcn_exp2f(sc[nf][3] - mrun[3]);
      u32x2 pk;
      pk.x = (u32)(unsigned short)cvt1(p0) | ((u32)(unsigned short)cvt1(p1) << 16);
      pk.y = (u32)(unsigned short)cvt1(p2) | ((u32)(unsigned short)cvt1(p3) << 16);
      *(u32x2*)(&Ps[w][key*16 + hi*4]) = pk;
    }
    asm volatile("s_waitcnt lgkmcnt(0)" ::: "memory"); // wave-local write->read fence
    __builtin_amdgcn_sched_barrier(0);
    // A-frags via hw transpose read. Tile = 4 key-rows x 16 q (128B).
    // addr_l = tile_base + lq*8B  ->  lane gets tile[j][lq] = P[q=lq][key0+j].
    bf8_t pf[2];
    #pragma unroll
    for (int ks2 = 0; ks2 < 2; ks2++) {
      const short* base = &Ps[w][(ks2*32 + hi*8)*16 + lq*4];
      u32x2 t0 = tr16(base);          // keys +0..3
      u32x2 t1 = tr16(base + 64);     // keys +4..7 (next 4x16 tile)
      union { bf8_t v8; u32x4 u4; } pu;
      pu.u4.x = t0.x; pu.u4.y = t0.y; pu.u4.z = t1.x; pu.u4.w = t1.y;
      pf[ks2] = pu.v8;
    }
    asm volatile("s_waitcnt lgkmcnt(0)" ::: "memory"); // tr reads complete (rule 18)
    __builtin_amdgcn_sched_barrier(0);
    // row-sum via MFMA-with-ones (accumulates across tiles)
    lacc = __builtin_amdgcn_mfma_f32_16x16x32_bf16(pf[0], ones, lacc, 0, 0, 0);
    lacc = __builtin_amdgcn_mfma_f32_16x16x32_bf16(pf[1], ones, lacc, 0, 0, 0);
    // PV: o += P (16q x 64k) . V^T (64hd x 64k)
    #pragma unroll
    for (int nf2 = 0; nf2 < 4; nf2++) {
      const int vr = nf2*16 + lq;
      #pragma unroll
      for (int ks2 = 0; ks2 < 2; ks2++) {
        bf8_t vf = *(const bf8_t*)(&Vs[cur][vr*64 + (((ks2*4 + hi) ^ (vr&7))*8)]);
        o[nf2] = __builtin_amdgcn_mfma_f32_16x16x32_bf16(pf[ks2], vf, o[nf2], 0, 0, 0);
      }
    }
    __syncthreads();
  }

  // epilogue: normalize and write h[b][s][h*64+hd] (f32)
  #pragma unroll
  for (int nf2 = 0; nf2 < 4; nf2++)
    #pragma unroll
    for (int r = 0; r < 4; r++) {
      int srow = q0 + hi*4 + r;
      out[((size_t)(b*Ss + srow))*Dd + h*HD + nf2*16 + lq] = o[nf2][r] / lacc[r];
    }
}

// ---------------------------------------------------------------------------
extern "C" void kernel_launch(void* const* d_in, const int* in_sizes, int n_in,
                              void* d_out, int out_size, void* d_ws, size_t ws_size,
                              hipStream_t stream) {
  const float* x  = (const float*)d_in[0];
  const int* mask = (const int*)d_in[1];
  const float* Wq = (const float*)d_in[2];
  const float* bq = (const float*)d_in[3];
  const float* Wk = (const float*)d_in[4];
  const float* bk = (const float*)d_in[5];
  const float* Wv = (const float*)d_in[6];
  const float* bv = (const float*)d_in[7];
  float* out = (float*)d_out;

  // ws: Q | K | Vt (each 4.19M shorts) | xb (4.19M) | Wb (786K)  ~= 35 MB
  short* Qg = (short*)d_ws;
  short* Kg = Qg + (size_t)Bb*Hh*Ss*HD;
  short* Vt = Kg + (size_t)Bb*Hh*Ss*HD;
  short* xb = Vt + (size_t)Bb*Hh*Ss*HD;
  short* Wb = xb + (size_t)NX;

  convert_kernel<<<dim3((NX + NW)/2048), 256, 0, stream>>>(x, Wq, Wk, Wv, xb, Wb);
  qkv_proj_kernel<<<dim3(64, 24), 256, 0, stream>>>(xb, Wb, bq, bk, bv, Qg, Kg, Vt);
  attn_kernel<<<dim3(32, 32), 256, 0, stream>>>(Qg, Kg, Vt, mask, out);
}

// Round 6
// 98.144 us; speedup vs baseline: 2.1235x; 1.0640x over previous
//
#include <hip/hip_runtime.h>
#include <hip/hip_bf16.h>

#define Bb 4
#define Ss 2048
#define Dd 512
#define Hh 8
#define HD 64
#define NX (Bb*Ss*Dd)   // 4194304 x elems
#define NW (3*Dd*Dd)    // 786432 weight elems

typedef __attribute__((ext_vector_type(8))) short bf8_t;   // 8 bf16 (4 VGPRs) MFMA operand
typedef __attribute__((ext_vector_type(4))) float f4_t;    // MFMA accumulator
typedef unsigned int u32;
typedef __attribute__((ext_vector_type(4))) unsigned int u32x4;

typedef const unsigned int __attribute__((address_space(1)))* gas_t;
typedef unsigned int __attribute__((address_space(3)))* las_t;

#define LOG2E 1.44269504088896f
#define MBIAS_C (-10000.0f * LOG2E)

__device__ __forceinline__ short cvt1(float f) {           // f32 -> bf16 (native RNE)
  __hip_bfloat16 h = __float2bfloat16(f);
  union { __hip_bfloat16 hh; short ss; } u; u.hh = h; return u.ss;
}

__device__ __forceinline__ u32 pk2(float a, float b) {     // pack 2 bf16 into u32
  return (u32)(unsigned short)cvt1(a) | ((u32)(unsigned short)cvt1(b) << 16);
}

__device__ __forceinline__ bf8_t pack8(float4 f0, float4 f1) {
  bf8_t v;
  v[0]=cvt1(f0.x); v[1]=cvt1(f0.y); v[2]=cvt1(f0.z); v[3]=cvt1(f0.w);
  v[4]=cvt1(f1.x); v[5]=cvt1(f1.y); v[6]=cvt1(f1.z); v[7]=cvt1(f1.w);
  return v;
}

__device__ __forceinline__ void gload_lds16(const void* g, void* l) {
  __builtin_amdgcn_global_load_lds((gas_t)g, (las_t)l, 16, 0, 0);
}

// ---------------------------------------------------------------------------
// f32 -> bf16 conversion for x and the three weight matrices.
// ---------------------------------------------------------------------------
__global__ __launch_bounds__(256) void convert_kernel(
    const float* __restrict__ x, const float* __restrict__ Wq,
    const float* __restrict__ Wk, const float* __restrict__ Wv,
    short* __restrict__ xb, short* __restrict__ Wb)
{
  size_t i = ((size_t)blockIdx.x * 256 + threadIdx.x) * 8;
  const float* src; short* dst;
  if (i < (size_t)NX) { src = x + i; dst = xb + i; }
  else {
    size_t j = i - NX;
    int ws = (int)(j >> 18);                 // 262144 elems per W
    const float* W = (ws == 0) ? Wq : (ws == 1) ? Wk : Wv;
    src = W + (j & 0x3FFFF); dst = Wb + j;
  }
  float4 f0 = *(const float4*)src;
  float4 f1 = *(const float4*)(src + 4);
  *(bf8_t*)dst = pack8(f0, f1);
}

// ---------------------------------------------------------------------------
// QKV projection from bf16 x/W. grid (64, 12): 128-row x-tile, 128-col tile
// (= 2 heads); blockIdx.y = proj*4 + col-quarter. 2-phase dbuf via gload_lds.
// Q,K out [b][h][s][hd] (Q pre-scaled by log2e/8); V out [b][h][hd][s].
// ---------------------------------------------------------------------------
__global__ __launch_bounds__(256, 2) void qkv_proj_kernel(
    const short* __restrict__ xb, const short* __restrict__ Wb,
    const float* __restrict__ bq, const float* __restrict__ bk,
    const float* __restrict__ bv,
    short* __restrict__ Qg, short* __restrict__ Kg, short* __restrict__ Vtg)
{
  __shared__ short As[2][128*64];   // 16B-chunk XOR swizzle c^(row&7)
  __shared__ short Bs2[2][128*64];
  const int p = blockIdx.y >> 2;
  const short* __restrict__ W = Wb + (size_t)p * Dd * Dd;
  const float* __restrict__ bias = (p==0) ? bq : (p==1) ? bk : bv;
  const int m0 = blockIdx.x * 128;
  const int n0 = (blockIdx.y & 3) * 128;
  const int tid = threadIdx.x;
  const int lane = tid & 63, wid = tid >> 6;
  const int lq = lane & 15, hi = lane >> 4;
  const int wm = wid & 1, wn = wid >> 1;    // wave -> 64x64 sub-tile

  const short* aSrc[4];
  const short* bSrc[4];
  #pragma unroll
  for (int i = 0; i < 4; i++) {
    int slot = tid + i*256, row = slot >> 3, c = slot & 7;
    aSrc[i] = xb + (size_t)(m0 + row)*Dd + ((c ^ (row&7))*8);
    bSrc[i] = W  + (size_t)(n0 + row)*Dd + ((c ^ (row&7))*8);
  }

  const f4_t zero4 = {0.f, 0.f, 0.f, 0.f};
  f4_t acc[4][4];
  #pragma unroll
  for (int i = 0; i < 4; i++)
    #pragma unroll
    for (int j = 0; j < 4; j++) acc[i][j] = zero4;

  auto STAGE = [&](int bufi, int k0) {
    #pragma unroll
    for (int i = 0; i < 4; i++) {
      gload_lds16(aSrc[i] + k0, &As[bufi][(tid + i*256)*8]);
      gload_lds16(bSrc[i] + k0, &Bs2[bufi][(tid + i*256)*8]);
    }
  };

  STAGE(0, 0);
  __syncthreads();
  for (int kt = 0; kt < 8; kt++) {
    const int cur = kt & 1;
    if (kt < 7) STAGE(cur ^ 1, (kt + 1)*64);
    #pragma unroll
    for (int ks = 0; ks < 2; ks++) {
      const int cu = ks*4 + hi;
      bf8_t a[4], bfrag[4];
      #pragma unroll
      for (int mi = 0; mi < 4; mi++) {
        int row = wm*64 + mi*16 + lq;
        a[mi] = *(const bf8_t*)(&As[cur][row*64 + ((cu ^ (row&7))*8)]);
      }
      #pragma unroll
      for (int nf = 0; nf < 4; nf++) {
        int row = wn*64 + nf*16 + lq;
        bfrag[nf] = *(const bf8_t*)(&Bs2[cur][row*64 + ((cu ^ (row&7))*8)]);
      }
      #pragma unroll
      for (int mi = 0; mi < 4; mi++)
        #pragma unroll
        for (int nf = 0; nf < 4; nf++)
          acc[mi][nf] = __builtin_amdgcn_mfma_f32_16x16x32_bf16(a[mi], bfrag[nf], acc[mi][nf], 0, 0, 0);
    }
    __syncthreads();
  }

  const float qs = (p == 0) ? 0.125f * LOG2E : 1.0f;
  float badd[4];
  #pragma unroll
  for (int nf = 0; nf < 4; nf++) badd[nf] = bias[n0 + wn*64 + nf*16 + lq];
  #pragma unroll
  for (int mi = 0; mi < 4; mi++) {
    #pragma unroll
    for (int nf = 0; nf < 4; nf++) {
      const int col = n0 + wn*64 + nf*16 + lq;     // 0..511
      const int h = col >> 6, hd = col & 63;
      #pragma unroll
      for (int r = 0; r < 4; r++) {
        int mrow = m0 + wm*64 + mi*16 + hi*4 + r;  // C: col=lane&15, row=hi*4+r
        int bb = mrow >> 11, ss = mrow & (Ss-1);
        short val = cvt1((acc[mi][nf][r] + badd[nf]) * qs);
        if (p == 2)
          Vtg[(((size_t)bb*Hh + h)*HD + hd)*Ss + ss] = val;
        else if (p == 0)
          Qg[(((size_t)bb*Hh + h)*Ss + ss)*HD + hd] = val;
        else
          Kg[(((size_t)bb*Hh + h)*Ss + ss)*HD + hd] = val;
      }
    }
  }
}

// ---------------------------------------------------------------------------
// Flash attention fwd. grid (32, 32): blockIdx.x = b*8+h, blockIdx.y = 64-row
// q-tile. 4 waves x 16 q-rows, KV tiles of 64 keys, 2-phase dbuf staging.
// SWAPPED QK^T (mfma(K,Q)): lane holds P^T[key][q=lane&15]; PV A-fragments
// built fully in-register via v_permlane32_swap + ds_swizzle(lane^16) network
// (no P LDS buffer, no fences, no tr-reads). exp2-domain online softmax with
// scalar per-lane running max + defer-max (THR=11); row-sum via MFMA-ones.
// LDS = 32 KB -> 4 blocks/CU.
// ---------------------------------------------------------------------------
__global__ __launch_bounds__(256, 4) void attn_kernel(
    const short* __restrict__ Qg, const short* __restrict__ Kg,
    const short* __restrict__ Vtg, const int* __restrict__ mask,
    float* __restrict__ out)
{
  __shared__ short Ks[2][64*64];   // [key][hd], swizzled
  __shared__ short Vs[2][64*64];   // [hd][key], swizzled
  const int bh = blockIdx.x;
  const int b = bh >> 3, h = bh & 7;
  const int tid = threadIdx.x, lane = tid & 63, w = tid >> 6;
  const int hi = lane >> 4, lq = lane & 15, tau = hi & 1;
  const short* __restrict__ Qb = Qg + (size_t)bh * Ss * HD;
  const short* __restrict__ Kb = Kg + (size_t)bh * Ss * HD;
  const short* __restrict__ Vb = Vtg + (size_t)bh * HD * Ss;
  const int* __restrict__ maskb = mask + b * Ss;
  const int q0 = blockIdx.y * 64 + w * 16;

  // Q fragments (Q already scaled by 0.125*log2e): B-operand, row=lq
  bf8_t qf[2];
  #pragma unroll
  for (int ks = 0; ks < 2; ks++)
    qf[ks] = *(const bf8_t*)(Qb + (size_t)(q0 + lq)*HD + ks*32 + hi*8);

  const f4_t zero4 = {0.f, 0.f, 0.f, 0.f};
  f4_t o[4];
  #pragma unroll
  for (int j = 0; j < 4; j++) o[j] = zero4;
  f4_t lacc = zero4;                        // row-sum accumulator (MFMA-ones)
  float mrun = -1e30f;                      // running max for q = lane&15

  const bf8_t ones = {(short)0x3F80,(short)0x3F80,(short)0x3F80,(short)0x3F80,
                      (short)0x3F80,(short)0x3F80,(short)0x3F80,(short)0x3F80};

  // staging sources: linear LDS dest, swizzle pre-applied on SOURCE (G21)
  const int sA = tid, sB = tid + 256;
  const short* ksrcA = Kb + (size_t)(sA>>3)*HD + (((sA&7) ^ ((sA>>3)&7))*8);
  const short* ksrcB = Kb + (size_t)(sB>>3)*HD + (((sB&7) ^ ((sB>>3)&7))*8);
  const short* vsrcA = Vb + (size_t)(sA>>3)*Ss + (((sA&7) ^ ((sA>>3)&7))*8);
  const short* vsrcB = Vb + (size_t)(sB>>3)*Ss + (((sB&7) ^ ((sB>>3)&7))*8);

  auto STAGE = [&](int bufi, int kv) {
    gload_lds16(ksrcA + (size_t)kv*HD, &Ks[bufi][sA*8]);
    gload_lds16(ksrcB + (size_t)kv*HD, &Ks[bufi][sB*8]);
    gload_lds16(vsrcA + kv,            &Vs[bufi][sA*8]);
    gload_lds16(vsrcB + kv,            &Vs[bufi][sB*8]);
  };

  STAGE(0, 0);
  __syncthreads();
  for (int t = 0; t < Ss/64; t++) {
    const int cur = t & 1;
    if (t + 1 < Ss/64) STAGE(cur ^ 1, (t + 1)*64);
    const int mv = maskb[t*64 + lane];

    // swapped QK^T: sc[kb] = D[k][q], k=kb*16+hi*4+r, q=lq
    f4_t sc[4];
    #pragma unroll
    for (int kb = 0; kb < 4; kb++) {
      const int row = kb*16 + lq;
      bf8_t kf0 = *(const bf8_t*)(&Ks[cur][row*64 + ((hi       ^ (row&7))*8)]);
      bf8_t kf1 = *(const bf8_t*)(&Ks[cur][row*64 + (((4 + hi) ^ (row&7))*8)]);
      sc[kb] = __builtin_amdgcn_mfma_f32_16x16x32_bf16(kf0, qf[0], zero4, 0, 0, 0);
      sc[kb] = __builtin_amdgcn_mfma_f32_16x16x32_bf16(kf1, qf[1], sc[kb], 0, 0, 0);
    }
    if (__any(mv == 0)) {                             // masked keys (rare)
      float mbl = MBIAS_C * (1.0f - (float)mv);
      #pragma unroll
      for (int kb = 0; kb < 4; kb++)
        #pragma unroll
        for (int r = 0; r < 4; r++)
          sc[kb][r] += __shfl(mbl, kb*16 + hi*4 + r, 64);
    }
    // defer-max: local 16-value max vs scalar running max
    float lmax = sc[0][0];
    #pragma unroll
    for (int kb = 0; kb < 4; kb++)
      #pragma unroll
      for (int r = 0; r < 4; r++) lmax = fmaxf(lmax, sc[kb][r]);
    if (__any(lmax > mrun + 11.0f)) {                 // rare: reduce + rescale
      float rmax = fmaxf(lmax, __shfl_xor(lmax, 16, 64));
      rmax = fmaxf(rmax, __shfl_xor(rmax, 32, 64));
      float mnew = fmaxf(mrun, rmax);
      float sf = __builtin_amdgcn_exp2f(mrun - mnew); // first tile: -> 0
      mrun = mnew;
      float sfo[4];
      #pragma unroll
      for (int r = 0; r < 4; r++) sfo[r] = __shfl(sf, hi*4 + r, 64);
      #pragma unroll
      for (int r = 0; r < 4; r++) {
        lacc[r] *= sfo[r];
        #pragma unroll
        for (int nf = 0; nf < 4; nf++) o[nf][r] *= sfo[r];
      }
    }
    // P = exp2(sc - mrun) -> bf16 dword pairs Wd[kb][d] (keys kb*16+hi*4+2d+{0,1})
    u32 Wd[4][2];
    #pragma unroll
    for (int kb = 0; kb < 4; kb++) {
      float p0 = __builtin_amdgcn_exp2f(sc[kb][0] - mrun);
      float p1 = __builtin_amdgcn_exp2f(sc[kb][1] - mrun);
      float p2 = __builtin_amdgcn_exp2f(sc[kb][2] - mrun);
      float p3 = __builtin_amdgcn_exp2f(sc[kb][3] - mrun);
      Wd[kb][0] = pk2(p0, p1);
      Wd[kb][1] = pk2(p2, p3);
    }
    // in-register transpose network: dst dword m of pf[c] = keys c*32+hi*8+2m
    // src (kb=2c+e, hi_s, d): e -> sigma_dst, sigma_src -> tau_dst, m=2*tau_src+d
    bf8_t pf[2];
    #pragma unroll
    for (int c = 0; c < 2; c++) {
      u32 m_[4];
      #pragma unroll
      for (int d = 0; d < 2; d++) {
        u32 X = Wd[2*c][d], Y = Wd[2*c+1][d];
        asm volatile("v_permlane32_swap_b32 %0, %1" : "+v"(X), "+v"(Y));
        u32 Xs = (u32)__builtin_amdgcn_ds_swizzle((int)X, 0x401F); // lane^16
        u32 Ys = (u32)__builtin_amdgcn_ds_swizzle((int)Y, 0x401F);
        m_[d]     = tau ? Ys : X;
        m_[2 + d] = tau ? Y  : Xs;
      }
      union { bf8_t v8; u32x4 u4; } pu;
      pu.u4.x = m_[0]; pu.u4.y = m_[1]; pu.u4.z = m_[2]; pu.u4.w = m_[3];
      pf[c] = pu.v8;
    }
    // MFMA cluster: row-sum + PV
    __builtin_amdgcn_s_setprio(1);
    lacc = __builtin_amdgcn_mfma_f32_16x16x32_bf16(pf[0], ones, lacc, 0, 0, 0);
    lacc = __builtin_amdgcn_mfma_f32_16x16x32_bf16(pf[1], ones, lacc, 0, 0, 0);
    #pragma unroll
    for (int nf2 = 0; nf2 < 4; nf2++) {
      const int vr = nf2*16 + lq;
      #pragma unroll
      for (int ks2 = 0; ks2 < 2; ks2++) {
        bf8_t vf = *(const bf8_t*)(&Vs[cur][vr*64 + (((ks2*4 + hi) ^ (vr&7))*8)]);
        o[nf2] = __builtin_amdgcn_mfma_f32_16x16x32_bf16(pf[ks2], vf, o[nf2], 0, 0, 0);
      }
    }
    __builtin_amdgcn_s_setprio(0);
    __syncthreads();
  }

  // epilogue: normalize and write h[b][s][h*64+hd] (f32)
  #pragma unroll
  for (int nf2 = 0; nf2 < 4; nf2++)
    #pragma unroll
    for (int r = 0; r < 4; r++) {
      int srow = q0 + hi*4 + r;
      out[((size_t)(b*Ss + srow))*Dd + h*HD + nf2*16 + lq] = o[nf2][r] / lacc[r];
    }
}

// ---------------------------------------------------------------------------
extern "C" void kernel_launch(void* const* d_in, const int* in_sizes, int n_in,
                              void* d_out, int out_size, void* d_ws, size_t ws_size,
                              hipStream_t stream) {
  const float* x  = (const float*)d_in[0];
  const int* mask = (const int*)d_in[1];
  const float* Wq = (const float*)d_in[2];
  const float* bq = (const float*)d_in[3];
  const float* Wk = (const float*)d_in[4];
  const float* bk = (const float*)d_in[5];
  const float* Wv = (const float*)d_in[6];
  const float* bv = (const float*)d_in[7];
  float* out = (float*)d_out;

  // ws: Q | K | Vt (each 4.19M shorts) | xb (4.19M) | Wb (786K)  ~= 35 MB
  short* Qg = (short*)d_ws;
  short* Kg = Qg + (size_t)Bb*Hh*Ss*HD;
  short* Vt = Kg + (size_t)Bb*Hh*Ss*HD;
  short* xb = Vt + (size_t)Bb*Hh*Ss*HD;
  short* Wb = xb + (size_t)NX;

  convert_kernel<<<dim3((NX + NW)/2048), 256, 0, stream>>>(x, Wq, Wk, Wv, xb, Wb);
  qkv_proj_kernel<<<dim3(64, 12), 256, 0, stream>>>(xb, Wb, bq, bk, bv, Qg, Kg, Vt);
  attn_kernel<<<dim3(32, 32), 256, 0, stream>>>(Qg, Kg, Vt, mask, out);
}